// Round 12
// baseline (243.540 us; speedup 1.0000x reference)
//
#include <hip/hip_runtime.h>
#include <math.h>

// y[b,h,l] = (u *causal* f)[l] + u[b,h,l]*D_skip[h] + init[h,l]
// State-space scan: s = lambda*s + q*u;  y = 2dt*sum_d Re(s) + u*Dk
// lambda_d = exp((a_d + i*theta_d)*dt); init folded into s's initial state.
//
// block = 256 threads = one (b,h) row; thread = (chunk j = tid>>2 of 64 elems,
// d-group g = tid&3 of DT=8 states, packed as NP=4 float2 pairs -> v_pk_fma_f32).
// u staged once in LDS; both passes read it via broadcast ds_read_b128.
// Kogge-Stone shuffle scan over chunks + LDS inter-wave carry.
// Quad-perm DPP adds for the 4-lane reduce.
//
// THIS ROUND: no LDS pad (18.4KB -> 8 blocks/CU), waves_per_eu(6,8) for an
// ~85-reg budget, and av/tv reloaded from L2 at the entry phase instead of
// held live across pass A + scan (peak live ~70 regs -> no spill).

#define Hn  256
#define Ln  4096
#define Dn  32
#define DT  8       // d-states per thread (4 packed pairs)
#define NP  4       // DT/2 packed pairs
#define LC  64      // elements per chunk
#define TPB 256
#define CS  68      // LDS chunk stride in floats (skew -> conflict-free)

typedef float v2 __attribute__((ext_vector_type(2)));

__device__ __forceinline__ v2 pfma(v2 a, v2 b, v2 c) {
    return __builtin_elementwise_fma(a, b, c);
}
__device__ __forceinline__ float dpp_add_x1(float v) {   // v += lane^1 (quad_perm)
    int t = __builtin_amdgcn_update_dpp(0, __float_as_int(v), 0xB1, 0xF, 0xF, true);
    return v + __int_as_float(t);
}
__device__ __forceinline__ float dpp_add_x2(float v) {   // v += lane^2 (quad_perm)
    int t = __builtin_amdgcn_update_dpp(0, __float_as_int(v), 0x4E, 0xF, 0xF, true);
    return v + __int_as_float(t);
}

__global__ __launch_bounds__(TPB)
__attribute__((amdgpu_waves_per_eu(6, 8)))
void hyena_scan(
    const float* __restrict__ u,      // (B,H,L)
    const float* __restrict__ ain,    // (1,H,D)
    const float* __restrict__ thin,   // (1,H,D)
    const float* __restrict__ bin,    // (1,H,D)
    const float* __restrict__ cin,    // (1,H,D)
    const float* __restrict__ x0in,   // (1,H,D)
    const float* __restrict__ Dsk,    // (1,H)
    float* __restrict__ out)          // (B,H,L)
{
    __shared__ float uL[64 * CS];     // 17408 B: u staged for both passes
    __shared__ float WTr[4][Dn];      // per-wave chunk-scan totals (re)
    __shared__ float WTi[4][Dn];      // per-wave chunk-scan totals (im)

    const int bh   = blockIdx.x;
    const int h    = bh & (Hn - 1);
    const int tid  = threadIdx.x;
    const int g    = tid & 3;         // d-group
    const int j    = tid >> 2;        // chunk 0..63
    const int m    = j & 15;          // chunk within wave
    const int wid  = tid >> 6;        // wave 0..3
    const int lane = tid & 63;
    const float dt   = 1.0f / (float)(Ln - 1);
    const float dt64 = dt * (float)LC;

    // ---- stage u into LDS (fully coalesced global reads) ----
    {
        const float4* ug = (const float4*)(u + (size_t)bh * Ln);
        #pragma unroll
        for (int r = 0; r < 4; ++r) {
            int i  = tid + r * TPB;          // float4 index 0..1023
            int cj = i >> 4, ct = i & 15;
            *(float4*)(uL + cj * CS + ct * 4) = ug[i];
        }
    }

    // ---- prologue: packed q, lambda^1, lambda^64 (no av/tv arrays kept) ----
    v2 q2[NP], lr2[NP], li2[NP], pr2[NP], pi2[NP];
    {
        const int cbase = h * Dn + g * DT;
        #pragma unroll
        for (int p = 0; p < NP; ++p) {
            #pragma unroll
            for (int k = 0; k < 2; ++k) {
                const int dd = 2 * p + k;
                float av = -fabsf(ain[cbase + dd]);
                float tv = thin[cbase + dd];
                float qk = bin[cbase + dd] * cin[cbase + dd];
                float e1 = __expf(av * dt);
                float s1, c1; __sincosf(tv * dt, &s1, &c1);
                float e2 = __expf(av * dt64);
                float s2, c2; __sincosf(tv * dt64, &s2, &c2);
                if (k == 0) {
                    q2[p].x = qk; lr2[p].x = e1 * c1; li2[p].x = e1 * s1;
                    pr2[p].x = e2 * c2; pi2[p].x = e2 * s2;
                } else {
                    q2[p].y = qk; lr2[p].y = e1 * c1; li2[p].y = e1 * s1;
                    pr2[p].y = e2 * c2; pi2[p].y = e2 * s2;
                }
            }
        }
    }
    __syncthreads();

    const float* uLc = uL + j * CS;

    // ---- pass A: local G-scan from zero (packed pairs) ----
    v2 gr2[NP], gi2[NP];
    const v2 zero2 = (v2){0.f, 0.f};
    #pragma unroll
    for (int p = 0; p < NP; ++p) { gr2[p] = zero2; gi2[p] = zero2; }

    #pragma unroll
    for (int kk = 0; kk < 16; ++kk) {
        float4 uf = *(const float4*)(uLc + kk * 4);
        float uu[4] = {uf.x, uf.y, uf.z, uf.w};
        #pragma unroll
        for (int c = 0; c < 4; ++c) {
            v2 uu2 = (v2){uu[c], uu[c]};
            #pragma unroll
            for (int p = 0; p < NP; ++p) {
                v2 t  = pfma(-li2[p], gi2[p], uu2);
                v2 nr = pfma(lr2[p], gr2[p], t);
                gi2[p] = pfma(lr2[p], gi2[p], li2[p] * gr2[p]);
                gr2[p] = nr;
            }
        }
    }

    // ---- intra-wave Kogge-Stone scan over 16 chunks (packed) ----
    #pragma unroll
    for (int st = 1; st < 16; st <<= 1) {
        int src = lane - st * 4; if (src < 0) src = lane;
        #pragma unroll
        for (int p = 0; p < NP; ++p) {
            v2 vr, vi;
            vr.x = __shfl(gr2[p].x, src, 64);
            vr.y = __shfl(gr2[p].y, src, 64);
            vi.x = __shfl(gi2[p].x, src, 64);
            vi.y = __shfl(gi2[p].y, src, 64);
            vr = (m >= st) ? vr : zero2;
            vi = (m >= st) ? vi : zero2;
            gr2[p] = pfma(pr2[p], vr, pfma(-pi2[p], vi, gr2[p]));
            gi2[p] = pfma(pr2[p], vi, pfma( pi2[p], vr, gi2[p]));
        }
        #pragma unroll
        for (int p = 0; p < NP; ++p) {        // p <- p^2
            v2 nr = pfma(pr2[p], pr2[p], -(pi2[p] * pi2[p]));
            v2 ni = (v2){2.f, 2.f} * (pr2[p] * pi2[p]);
            pr2[p] = nr; pi2[p] = ni;
        }
    }
    // pr2/pi2 now = lambda^1024 (wave-span multiplier)

    // ---- inter-wave carry via LDS (SoA, b64 pair loads) ----
    if (m == 15) {
        #pragma unroll
        for (int p = 0; p < NP; ++p) {
            const int i0 = g * DT + 2 * p;
            WTr[wid][i0]     = gr2[p].x;  WTr[wid][i0 + 1] = gr2[p].y;
            WTi[wid][i0]     = gi2[p].x;  WTi[wid][i0 + 1] = gi2[p].y;
        }
    }
    __syncthreads();
    v2 cr2[NP], ci2[NP];
    #pragma unroll
    for (int p = 0; p < NP; ++p) { cr2[p] = zero2; ci2[p] = zero2; }
    for (int v = 0; v < wid; ++v) {           // wave-uniform trip count
        #pragma unroll
        for (int p = 0; p < NP; ++p) {
            const int i0 = g * DT + 2 * p;
            v2 tr = *(const v2*)&WTr[v][i0];
            v2 ti = *(const v2*)&WTi[v][i0];
            v2 nr = pfma(pr2[p], cr2[p], pfma(-pi2[p], ci2[p], tr));
            v2 ni = pfma(pr2[p], ci2[p], pfma( pi2[p], cr2[p], ti));
            cr2[p] = nr; ci2[p] = ni;
        }
    }

    // ---- entry state: s = q*(excl + lambda^(64m)*carry) + w*lambda^(j*64-1) ----
    // av/tv RELOADED from L2-resident coefficient arrays (not held live above).
    {
        int src4 = lane - 4; if (src4 < 0) src4 = lane;
        const float t1 = dt * (float)(j * LC - 1);
        const float tm = dt64 * (float)m;
        const int cbase = h * Dn + g * DT;
        #pragma unroll
        for (int p = 0; p < NP; ++p) {
            float s0r[2], s0i[2];
            #pragma unroll
            for (int k = 0; k < 2; ++k) {
                const int dd = 2 * p + k;
                float av = -fabsf(ain[cbase + dd]);
                float tv = thin[cbase + dd];
                float grk = (k == 0) ? gr2[p].x : gr2[p].y;
                float gik = (k == 0) ? gi2[p].x : gi2[p].y;
                float crk = (k == 0) ? cr2[p].x : cr2[p].y;
                float cik = (k == 0) ? ci2[p].x : ci2[p].y;
                float qk  = (k == 0) ? q2[p].x  : q2[p].y;
                float er = __shfl(grk, src4, 64);     // exclusive intra-wave scan
                float ei = __shfl(gik, src4, 64);
                er = (m >= 1) ? er : 0.0f;
                ei = (m >= 1) ? ei : 0.0f;
                float e3 = __expf(av * tm);
                float s3, c3; __sincosf(tv * tm, &s3, &c3);
                float amr = e3 * c3, ami = e3 * s3;
                float enr = er + fmaf(amr, crk, -(ami * cik));
                float eni = ei + fmaf(amr, cik,  (ami * crk));
                float w  = 2.0f * cin[cbase + dd] * x0in[cbase + dd];
                float e4 = __expf(av * t1);
                float s4, c4; __sincosf(tv * t1, &s4, &c4);
                s0r[k] = fmaf(qk, enr, w * e4 * c4);
                s0i[k] = fmaf(qk, eni, w * e4 * s4);
            }
            gr2[p] = (v2){s0r[0], s0r[1]};            // reuse gr2/gi2 as s
            gi2[p] = (v2){s0i[0], s0i[1]};
        }
    }

    // ---- pass B: packed s-scan (u from LDS), DPP 4-lane reduce, store ----
    const float Dk = Dsk[h];
    const float two_dt = 2.0f * dt;
    float4* o4g = (float4*)(out + (size_t)bh * Ln) + j * 16;

    #pragma unroll
    for (int kb = 0; kb < 4; ++kb) {
        float ovv[4];
        #pragma unroll
        for (int sg = 0; sg < 4; ++sg) {
            float4 uf = *(const float4*)(uLc + (kb * 4 + sg) * 4);
            float uu[4] = {uf.x, uf.y, uf.z, uf.w};
            #pragma unroll
            for (int c = 0; c < 4; ++c) {
                float uval = uu[c];
                v2 uu2 = (v2){uval, uval};
                v2 acc = zero2;
                #pragma unroll
                for (int p = 0; p < NP; ++p) {
                    v2 mq = q2[p] * uu2;
                    v2 t  = pfma(-li2[p], gi2[p], mq);
                    v2 nr = pfma(lr2[p], gr2[p], t);
                    gi2[p] = pfma(lr2[p], gi2[p], li2[p] * gr2[p]);
                    gr2[p] = nr;
                    acc = acc + nr;
                }
                float ps = acc.x + acc.y;
                ps = dpp_add_x1(ps);
                ps = dpp_add_x2(ps);               // full 4-lane sum
                float y = fmaf(uval, Dk, two_dt * ps);
                if (sg == g) ovv[c] = y;
            }
        }
        float4 ov; ov.x = ovv[0]; ov.y = ovv[1]; ov.z = ovv[2]; ov.w = ovv[3];
        o4g[kb * 4 + g] = ov;
    }
}

extern "C" void kernel_launch(void* const* d_in, const int* in_sizes, int n_in,
                              void* d_out, int out_size, void* d_ws, size_t ws_size,
                              hipStream_t stream) {
    const float* u   = (const float*)d_in[0];
    const float* a   = (const float*)d_in[1];
    const float* th  = (const float*)d_in[2];
    const float* b   = (const float*)d_in[3];
    const float* c   = (const float*)d_in[4];
    const float* x0  = (const float*)d_in[5];
    const float* Dsk = (const float*)d_in[6];
    float* out = (float*)d_out;

    hipLaunchKernelGGL(hyena_scan, dim3(16 * Hn), dim3(TPB), 0, stream,
                       u, a, th, b, c, x0, Dsk, out);
}